// Round 3
// baseline (671.628 us; speedup 1.0000x reference)
//
#include <hip/hip_runtime.h>

#define N_ 32
#define C_ 128
#define H_ 32
#define W_ 32
#define T_ 12
#define R_ 64
#define HW_ (H_*W_)           // 1024
#define HWT_ (HW_*T_)         // 12288
#define CHWT_ ((size_t)C_*HW_*T_)  // 1572864
#define TSPART_ (N_*T_*HW_)   // 393216 floats per c-group partial

__device__ __forceinline__ float sigm(float v) {
    return 1.0f / (1.0f + __expf(-v));
}

// K1a: ts_part[g][n,t,h,w] = sum_{c in group g} x[n,c,h,w,t]  (4 c-groups of 32)
__global__ __launch_bounds__(256) void k_tsin(const float* __restrict__ x,
                                              float* __restrict__ ts_part) {
    int bx = blockIdx.x;          // 0..63
    int chunk = bx & 15;
    int g = bx >> 4;              // 0..3
    int n = blockIdx.y;
    int tid = threadIdx.x;
    int hw0 = chunk * 64;
    const float* xp = x + (size_t)n * CHWT_ + (size_t)hw0 * T_ + (size_t)g * 32 * HWT_;
    float s0 = 0.f, s1 = 0.f, s2 = 0.f;
    #pragma unroll 4
    for (int c = 0; c < 32; ++c) {
        const float* p = xp + (size_t)c * HWT_;
        s0 += p[tid];
        s1 += p[tid + 256];
        s2 += p[tid + 512];
    }
    float sums[3] = {s0, s1, s2};
    #pragma unroll
    for (int j = 0; j < 3; ++j) {
        int p = tid + 256 * j;
        int hwl = p / T_;
        int t = p - hwl * T_;
        ts_part[(size_t)g * TSPART_ + (n * T_ + t) * HW_ + hw0 + hwl] = sums[j];
    }
}

// K1b: pooled[n,t,c] = mean_{hw} x[n,c,hw,t]; block per (c,n).
// Deterministic LDS-array reduction (no atomics).
__global__ __launch_bounds__(256) void k_pool(const float* __restrict__ x,
                                              float* __restrict__ pooled) {
    int c = blockIdx.x;
    int n = blockIdx.y;
    int tid = threadIdx.x;
    const float* xp = x + (size_t)(n * C_ + c) * HWT_;
    float a0 = 0.f, a1 = 0.f, a2 = 0.f;
    #pragma unroll 4
    for (int k = 0; k < 48; k += 3) {
        a0 += xp[tid + 256 * k];
        a1 += xp[tid + 256 * (k + 1)];
        a2 += xp[tid + 256 * (k + 2)];
    }
    __shared__ float arr[3 * 256];
    arr[tid] = a0;
    arr[256 + tid] = a1;
    arr[512 + tid] = a2;
    __syncthreads();
    if (tid < T_) {
        // arr[j*256+p] belongs to t = (p + 4j) % 12
        float s = 0.f;
        #pragma unroll
        for (int j = 0; j < 3; ++j) {
            int rho = ((tid - 4 * j) + 12) % 12;
            for (int p = rho; p < 256; p += 12) s += arr[j * 256 + p];
        }
        pooled[(n * T_ + tid) * C_ + c] = s * (1.0f / 1024.0f);
    }
}

// K2: TS[n,r,s] = sigmoid(conv3x3(ts_in)[n,r,h,w] + ts_b[r]); sums 4 ts_part partials in staging.
__global__ __launch_bounds__(256) void k_conv(const float* __restrict__ ts_part,
                                              const float* __restrict__ ts_w,
                                              const float* __restrict__ ts_b,
                                              float* __restrict__ TS) {
    int h = blockIdx.x;
    int n = blockIdx.y;
    int tid = threadIdx.x;
    __shared__ float rows[3 * T_ * 34];   // 1224 floats
    __shared__ float wl[R_ * 108];        // 6912 floats
    for (int i = tid; i < 3 * T_ * 34; i += 256) {
        int kh = i / (T_ * 34);
        int rem = i - kh * (T_ * 34);
        int t = rem / 34;
        int wp = rem - t * 34;
        int hr = h + kh - 1;
        float v = 0.f;
        if (wp >= 1 && wp <= 32 && hr >= 0 && hr < H_) {
            int idx = ((n * T_ + t) * H_ + hr) * W_ + (wp - 1);
            v = (ts_part[idx] + ts_part[TSPART_ + idx] +
                 ts_part[2 * TSPART_ + idx] + ts_part[3 * TSPART_ + idx]) * 0.0078125f;
        }
        rows[i] = v;
    }
    for (int i = tid; i < R_ * 108; i += 256) wl[i] = ts_w[i];
    __syncthreads();
    int r = tid >> 2;
    int j = tid & 3;
    float acc[8];
    float b = ts_b[r];
    #pragma unroll
    for (int wi = 0; wi < 8; ++wi) acc[wi] = b;
    for (int t = 0; t < T_; ++t) {
        #pragma unroll
        for (int kh = 0; kh < 3; ++kh) {
            #pragma unroll
            for (int kw = 0; kw < 3; ++kw) {
                float wt = wl[r * 108 + t * 9 + kh * 3 + kw];
                const float* rp = &rows[(kh * T_ + t) * 34 + kw];
                #pragma unroll
                for (int wi = 0; wi < 8; ++wi) {
                    acc[wi] += rp[j + 4 * wi] * wt;
                }
            }
        }
    }
    float* outp = TS + (size_t)(n * R_ + r) * HW_ + h * W_;
    #pragma unroll
    for (int wi = 0; wi < 8; ++wi) {
        outp[j + 4 * wi] = sigm(acc[wi]);
    }
}

// K3: TC[n,t,r] and SC[n,c,r]; block per n.
__global__ __launch_bounds__(256) void k_lin(const float* __restrict__ pooled,
                                             const float* __restrict__ tc_w,
                                             const float* __restrict__ tc_b,
                                             const float* __restrict__ sc_w,
                                             const float* __restrict__ sc_b,
                                             float* __restrict__ TC,
                                             float* __restrict__ SC) {
    int n = blockIdx.x;
    int tid = threadIdx.x;
    __shared__ float pl[T_ * C_];    // 1536
    __shared__ float twt[C_ * R_];   // 8192, [c][r]
    __shared__ float sw[R_ * T_];    // 768
    for (int i = tid; i < T_ * C_; i += 256) pl[i] = pooled[n * T_ * C_ + i];
    for (int i = tid; i < C_ * R_; i += 256) {
        int r = i >> 7;
        int c = i & 127;
        twt[c * R_ + r] = tc_w[i];
    }
    for (int i = tid; i < R_ * T_; i += 256) sw[i] = sc_w[i];
    __syncthreads();
    for (int o = tid; o < T_ * R_; o += 256) {
        int t = o >> 6;
        int r = o & 63;
        float acc = tc_b[r];
        #pragma unroll 4
        for (int c = 0; c < C_; ++c) acc += pl[t * C_ + c] * twt[c * R_ + r];
        TC[n * T_ * R_ + o] = sigm(acc);
    }
    for (int o = tid; o < C_ * R_; o += 256) {
        int c = o >> 6;
        int r = o & 63;
        float acc = sc_b[r];
        #pragma unroll
        for (int t = 0; t < T_; ++t) acc += pl[t * C_ + c] * sw[r * T_ + t];
        SC[n * C_ * R_ + o] = sigm(acc);
    }
}

// K4 v2: register-tiled rank-sum.
// block = (s-chunk 32, n), 256 threads. Thread: s = s0+(tid&31), cg = tid>>5,
// computes acc[12 t][16 c] over the full r=64 sum, then fused x-mult + relu + store.
// Per r-step LDS: 4 b128 (SC) + 3 b128 (TC) + 1 b32 (TS) ~= 90 cyc feeding
// 192 FMA + 16 mult (~432 VALU cyc): VALU-bound, LDS pipe ~84%.
__global__ __launch_bounds__(256, 2) void k_main(const float* __restrict__ x,
                                                 const float* __restrict__ TS,
                                                 const float* __restrict__ TC,
                                                 const float* __restrict__ SC,
                                                 float* __restrict__ out) {
    int schunk = blockIdx.x;   // 0..31
    int n = blockIdx.y;
    int tid = threadIdx.x;
    int s0 = schunk * 32;
    __shared__ __align__(16) float SCt[64 * 132];  // [r][c], padded stride 132
    __shared__ __align__(16) float TCt[64 * 16];   // [r][t], 12 used of 16
    __shared__ float TSs[64 * 32];                 // [r][sl]
    // stage SCt: SC[n][c][r] -> SCt[r*132+c]  (coalesced global read)
    for (int i = tid; i < C_ * R_; i += 256) {
        int c = i >> 6;
        int r = i & 63;
        SCt[r * 132 + c] = SC[(size_t)n * C_ * R_ + i];
    }
    // stage TCt: TC[n][t][r] -> TCt[r*16+t]
    for (int i = tid; i < T_ * R_; i += 256) {
        int t = i >> 6;
        int r = i & 63;
        TCt[r * 16 + t] = TC[n * T_ * R_ + i];
    }
    // stage TSs: TS[n][r][s0+sl]
    for (int i = tid; i < R_ * 32; i += 256) {
        int r = i >> 5;
        int sl = i & 31;
        TSs[i] = TS[(size_t)(n * R_ + r) * HW_ + s0 + sl];
    }
    __syncthreads();
    int sl = tid & 31;
    int cg = tid >> 5;       // 0..7
    int c0 = cg * 16;
    float acc[T_][16];
    #pragma unroll
    for (int t = 0; t < T_; ++t)
        #pragma unroll
        for (int j = 0; j < 16; ++j) acc[t][j] = 0.f;

    for (int r = 0; r < R_; ++r) {
        float ts = TSs[r * 32 + sl];
        const float4* scp = (const float4*)(SCt + r * 132 + c0);
        const float4* tcp = (const float4*)(TCt + r * 16);
        float4 tca = tcp[0], tcb = tcp[1], tcc = tcp[2];
        float tcv[T_] = {tca.x, tca.y, tca.z, tca.w,
                         tcb.x, tcb.y, tcb.z, tcb.w,
                         tcc.x, tcc.y, tcc.z, tcc.w};
        #pragma unroll
        for (int q = 0; q < 4; ++q) {
            float4 sc = scp[q];
            float p0 = sc.x * ts, p1 = sc.y * ts, p2 = sc.z * ts, p3 = sc.w * ts;
            #pragma unroll
            for (int t = 0; t < T_; ++t) {
                acc[t][4 * q + 0] += p0 * tcv[t];
                acc[t][4 * q + 1] += p1 * tcv[t];
                acc[t][4 * q + 2] += p2 * tcv[t];
                acc[t][4 * q + 3] += p3 * tcv[t];
            }
        }
    }
    // epilogue: out[n,c,s,t] = relu(acc[t][c] * x[n,c,s,t]), 12 contiguous t = 3 float4
    size_t sbase = (size_t)n * CHWT_ + (size_t)(s0 + sl) * T_;
    #pragma unroll 2
    for (int j = 0; j < 16; ++j) {
        int c = c0 + j;
        const float4* xp = (const float4*)(x + sbase + (size_t)c * HWT_);
        float4* op = (float4*)(out + sbase + (size_t)c * HWT_);
        float4 x0 = xp[0], x1 = xp[1], x2 = xp[2];
        float4 o0, o1, o2;
        o0.x = fmaxf(acc[0][j] * x0.x, 0.f);
        o0.y = fmaxf(acc[1][j] * x0.y, 0.f);
        o0.z = fmaxf(acc[2][j] * x0.z, 0.f);
        o0.w = fmaxf(acc[3][j] * x0.w, 0.f);
        o1.x = fmaxf(acc[4][j] * x1.x, 0.f);
        o1.y = fmaxf(acc[5][j] * x1.y, 0.f);
        o1.z = fmaxf(acc[6][j] * x1.z, 0.f);
        o1.w = fmaxf(acc[7][j] * x1.w, 0.f);
        o2.x = fmaxf(acc[8][j] * x2.x, 0.f);
        o2.y = fmaxf(acc[9][j] * x2.y, 0.f);
        o2.z = fmaxf(acc[10][j] * x2.z, 0.f);
        o2.w = fmaxf(acc[11][j] * x2.w, 0.f);
        op[0] = o0; op[1] = o1; op[2] = o2;
    }
}

extern "C" void kernel_launch(void* const* d_in, const int* in_sizes, int n_in,
                              void* d_out, int out_size, void* d_ws, size_t ws_size,
                              hipStream_t stream) {
    const float* x    = (const float*)d_in[0];
    const float* ts_w = (const float*)d_in[1];
    const float* ts_b = (const float*)d_in[2];
    const float* tc_w = (const float*)d_in[3];
    const float* tc_b = (const float*)d_in[4];
    const float* sc_w = (const float*)d_in[5];
    const float* sc_b = (const float*)d_in[6];
    float* out = (float*)d_out;

    float* ws      = (float*)d_ws;
    float* ts_part = ws;                          // 4*393216 = 1572864 floats
    float* pooled  = ts_part + 4 * TSPART_;       // 49152
    float* TS      = pooled + 49152;              // 2097152
    float* TC      = TS + 2097152;                // 24576
    float* SC      = TC + 24576;                  // 262144   (total ~16 MB)

    hipLaunchKernelGGL(k_tsin, dim3(64, 32), dim3(256), 0, stream, x, ts_part);
    hipLaunchKernelGGL(k_pool, dim3(128, 32), dim3(256), 0, stream, x, pooled);
    hipLaunchKernelGGL(k_conv, dim3(32, 32), dim3(256), 0, stream, ts_part, ts_w, ts_b, TS);
    hipLaunchKernelGGL(k_lin, dim3(32), dim3(256), 0, stream,
                       pooled, tc_w, tc_b, sc_w, sc_b, TC, SC);
    hipLaunchKernelGGL(k_main, dim3(32, 32), dim3(256), 0, stream, x, TS, TC, SC, out);
}